// Round 4
// baseline (216.879 us; speedup 1.0000x reference)
//
#include <hip/hip_runtime.h>
#include <hip/hip_bf16.h>
#include <math.h>

#define EMBED 1024
#define HDIM  64
#define BATCH 4
#define SEQ   2048

typedef __attribute__((ext_vector_type(8))) short short8;
typedef __attribute__((ext_vector_type(4))) float f32x4;
typedef unsigned int u32;
typedef unsigned short u16;

static __device__ __forceinline__ u16 f2bf(float f) {
    union { float f; u32 u; } v; v.f = f;
    u32 r = v.u + 0x7fffu + ((v.u >> 16) & 1u);  // round-to-nearest-even
    return (u16)(r >> 16);
}

// async global->LDS, 16B per lane. LDS dest must equal uniform_base + lane*16.
static __device__ __forceinline__ void gload_lds16(const u16* g, u16* l) {
    __builtin_amdgcn_global_load_lds(
        (const __attribute__((address_space(1))) u32*)g,
        (__attribute__((address_space(3))) u32*)l, 16, 0, 0);
}

// ---------------------------------------------------------------------------
// K0: WqT[d][e] = bf16(Wq[e][d]), WkT likewise. grid (16,2) x 256.
// ---------------------------------------------------------------------------
__global__ __launch_bounds__(256) void wt_kernel(
    const float* __restrict__ Wq, const float* __restrict__ Wk,
    u16* __restrict__ WqT, u16* __restrict__ WkT)
{
    __shared__ float tile[64][65];
    const float* W = blockIdx.y ? Wk : Wq;
    u16* WT = blockIdx.y ? WkT : WqT;
    int e0 = blockIdx.x * 64;
    int t = threadIdx.x, c = t & 63, r4 = t >> 6;
    for (int r = r4; r < 64; r += 4)
        tile[r][c] = W[(size_t)(e0 + r) * HDIM + c];   // tile[e-e0][d]
    __syncthreads();
    for (int d = r4; d < 64; d += 4)
        WT[(size_t)d * EMBED + e0 + c] = f2bf(tile[c][d]);
}

// ---------------------------------------------------------------------------
// K1: proj + transpose fused. Q = 0.125*(h*Wq+bq), K = h*Wk+bk, hT = bf16(h)^T.
// grid 512 (B * S/16), 256 thr, 16 s-rows/block. Single pass over h.
// Double-buffered LDS ping-pong => ONE barrier per iteration.
// ---------------------------------------------------------------------------
__global__ __launch_bounds__(256) void proj_kernel(
    const float* __restrict__ h, const u16* __restrict__ WqT, const u16* __restrict__ WkT,
    const float* __restrict__ bq, const float* __restrict__ bk,
    u16* __restrict__ Qbf, u16* __restrict__ Kbf, u16* __restrict__ hT)
{
    __shared__ u16 hs[2][16][72];
    int b = blockIdx.x >> 7, s0 = (blockIdx.x & 127) * 16;
    int t = threadIdx.x, lane = t & 63, w = t >> 6;
    int l15 = lane & 15, quad = lane >> 4;
    int pj = w >> 1, nh = (w & 1) * 32;
    const float* hb = h + ((size_t)b * SEQ + s0) * EMBED;
    u16* hTb = hT + (size_t)b * EMBED * SEQ;
    const u16* Wp = pj ? WkT : WqT;
    int r = t >> 4, c4 = (t & 15) * 4;     // staging role: 16 rows x 16 float4
    int ej = t >> 2, soff = (t & 3) * 4;   // transpose-write role: 64 e-rows x 4 s

    f32x4 pre = *(const f32x4*)(hb + (size_t)r * EMBED + c4);
    f32x4 acc[2];
    acc[0] = acc[1] = (f32x4){0.f, 0.f, 0.f, 0.f};

    const u16* Wrow0 = Wp + (size_t)(nh + l15) * EMBED;
    const u16* Wrow1 = Wp + (size_t)(nh + 16 + l15) * EMBED;

    for (int it = 0; it < 16; ++it) {
        int ec = it * 64, buf = it & 1;
        uint2 pk;
        pk.x = (u32)f2bf(pre[0]) | ((u32)f2bf(pre[1]) << 16);
        pk.y = (u32)f2bf(pre[2]) | ((u32)f2bf(pre[3]) << 16);
        *(uint2*)&hs[buf][r][c4] = pk;
        __syncthreads();
        if (it + 1 < 16)
            pre = *(const f32x4*)(hb + (size_t)r * EMBED + ec + 64 + c4);

        // transposed write: e-row ec+ej, s-cols s0+soff..+3
        {
            u16 v0 = hs[buf][soff    ][ej];
            u16 v1 = hs[buf][soff + 1][ej];
            u16 v2 = hs[buf][soff + 2][ej];
            u16 v3 = hs[buf][soff + 3][ej];
            uint2 pk2;
            pk2.x = (u32)v0 | ((u32)v1 << 16);
            pk2.y = (u32)v2 | ((u32)v3 << 16);
            *(uint2*)(hTb + (size_t)(ec + ej) * SEQ + s0 + soff) = pk2;
        }

        short8 bf00 = *(const short8*)(Wrow0 + ec + quad * 8);
        short8 bf01 = *(const short8*)(Wrow0 + ec + 32 + quad * 8);
        short8 bf10 = *(const short8*)(Wrow1 + ec + quad * 8);
        short8 bf11 = *(const short8*)(Wrow1 + ec + 32 + quad * 8);
        short8 a0 = *(const short8*)&hs[buf][l15][quad * 8];
        short8 a1 = *(const short8*)&hs[buf][l15][32 + quad * 8];
        acc[0] = __builtin_amdgcn_mfma_f32_16x16x32_bf16(a0, bf00, acc[0], 0, 0, 0);
        acc[0] = __builtin_amdgcn_mfma_f32_16x16x32_bf16(a1, bf01, acc[0], 0, 0, 0);
        acc[1] = __builtin_amdgcn_mfma_f32_16x16x32_bf16(a0, bf10, acc[1], 0, 0, 0);
        acc[1] = __builtin_amdgcn_mfma_f32_16x16x32_bf16(a1, bf11, acc[1], 0, 0, 0);
        // no trailing barrier: next iter stages into buf^1; reuse of buf is
        // protected by the barrier two iterations ahead.
    }

    const float* bias = pj ? bk : bq;
    float scale = pj ? 1.0f : 0.125f;
    u16* outp = pj ? Kbf : Qbf;
    float bv0 = bias[nh + l15], bv1 = bias[nh + 16 + l15];
#pragma unroll
    for (int rr = 0; rr < 4; rr++) {
        size_t row = (size_t)b * SEQ + s0 + quad * 4 + rr;
        outp[row * HDIM + nh + l15]      = f2bf((acc[0][rr] + bv0) * scale);
        outp[row * HDIM + nh + 16 + l15] = f2bf((acc[1][rr] + bv1) * scale);
    }
}

// ---------------------------------------------------------------------------
// K2: column softmax stats (softmax over q): per-(b,k) m = max_q s, l = sum_q exp(s-m).
// grid (S/16, B) x 256; wave w covers q in [w*512, w*512+512); LDS combine.
// ---------------------------------------------------------------------------
__global__ __launch_bounds__(256) void stats_kernel(
    const u16* __restrict__ Qbf, const u16* __restrict__ Kbf,
    float* __restrict__ mArr, float* __restrict__ lArr)
{
    __shared__ float sm[4][16], sl[4][16];
    int b = blockIdx.y;
    int k0 = blockIdx.x * 16;
    int t = threadIdx.x, lane = t & 63, w = t >> 6;
    int l15 = lane & 15, quad = lane >> 4;
    const u16* Qb = Qbf + (size_t)b * SEQ * HDIM;
    const u16* Kb = Kbf + (size_t)b * SEQ * HDIM;
    short8 kf0 = *(const short8*)(Kb + (size_t)(k0 + l15) * HDIM + quad * 8);
    short8 kf1 = *(const short8*)(Kb + (size_t)(k0 + l15) * HDIM + 32 + quad * 8);
    float m_run = -1e30f, l_run = 0.f;
    int qs = w * 512;
    for (int q0 = qs; q0 < qs + 512; q0 += 16) {
        short8 qf0 = *(const short8*)(Qb + (size_t)(q0 + l15) * HDIM + quad * 8);
        short8 qf1 = *(const short8*)(Qb + (size_t)(q0 + l15) * HDIM + 32 + quad * 8);
        f32x4 acc = {0.f, 0.f, 0.f, 0.f};
        acc = __builtin_amdgcn_mfma_f32_16x16x32_bf16(qf0, kf0, acc, 0, 0, 0);
        acc = __builtin_amdgcn_mfma_f32_16x16x32_bf16(qf1, kf1, acc, 0, 0, 0);
        float tm = fmaxf(fmaxf(acc[0], acc[1]), fmaxf(acc[2], acc[3]));
        tm = fmaxf(tm, __shfl_xor(tm, 16, 64));
        tm = fmaxf(tm, __shfl_xor(tm, 32, 64));
        float mn = fmaxf(m_run, tm);
        float p = __expf(acc[0] - mn) + __expf(acc[1] - mn)
                + __expf(acc[2] - mn) + __expf(acc[3] - mn);
        p += __shfl_xor(p, 16, 64);
        p += __shfl_xor(p, 32, 64);
        l_run = l_run * __expf(m_run - mn) + p;
        m_run = mn;
    }
    if (quad == 0) { sm[w][l15] = m_run; sl[w][l15] = l_run; }
    __syncthreads();
    if (t < 16) {
        float m = fmaxf(fmaxf(sm[0][t], sm[1][t]), fmaxf(sm[2][t], sm[3][t]));
        float l = sl[0][t] * __expf(sm[0][t] - m) + sl[1][t] * __expf(sm[1][t] - m)
                + sl[2][t] * __expf(sm[2][t] - m) + sl[3][t] * __expf(sm[3][t] - m);
        mArr[b * SEQ + k0 + t] = m;
        lArr[b * SEQ + k0 + t] = l;
    }
}

// ---------------------------------------------------------------------------
// K3: Wmat[b][q][k] = bf16( exp(s - m[k]) / l[k] )
// grid (S/64, S/64, B); 4 waves, wave w = q-subtile w*16, loops 4 k-subtiles.
// ---------------------------------------------------------------------------
__global__ __launch_bounds__(256) void weights_kernel(
    const u16* __restrict__ Qbf, const u16* __restrict__ Kbf,
    const float* __restrict__ mArr, const float* __restrict__ lArr,
    u16* __restrict__ Wmat)
{
    int b = blockIdx.z;
    int q0 = blockIdx.x * 64, k0 = blockIdx.y * 64;
    int t = threadIdx.x, lane = t & 63, w = t >> 6;
    int l15 = lane & 15, quad = lane >> 4;
    const u16* Qb = Qbf + (size_t)b * SEQ * HDIM;
    const u16* Kb = Kbf + (size_t)b * SEQ * HDIM;
    int q = q0 + w * 16;
    short8 qf0 = *(const short8*)(Qb + (size_t)(q + l15) * HDIM + quad * 8);
    short8 qf1 = *(const short8*)(Qb + (size_t)(q + l15) * HDIM + 32 + quad * 8);
    u16* Wb = Wmat + (size_t)b * SEQ * SEQ;
#pragma unroll
    for (int kt = 0; kt < 4; kt++) {
        int k = k0 + kt * 16;
        short8 kf0 = *(const short8*)(Kb + (size_t)(k + l15) * HDIM + quad * 8);
        short8 kf1 = *(const short8*)(Kb + (size_t)(k + l15) * HDIM + 32 + quad * 8);
        f32x4 acc = {0.f, 0.f, 0.f, 0.f};
        acc = __builtin_amdgcn_mfma_f32_16x16x32_bf16(qf0, kf0, acc, 0, 0, 0);
        acc = __builtin_amdgcn_mfma_f32_16x16x32_bf16(qf1, kf1, acc, 0, 0, 0);
        float mv  = mArr[b * SEQ + k + l15];
        float inv = 1.0f / lArr[b * SEQ + k + l15];
#pragma unroll
        for (int r = 0; r < 4; r++) {
            float wv = __expf(acc[r] - mv) * inv;
            Wb[(size_t)(q + quad * 4 + r) * SEQ + k + l15] = f2bf(wv);
        }
    }
}

// ---------------------------------------------------------------------------
// K4: out[b][q][e] = sum_k Wmat[b][q][k] * hT[b][e][k]
// 128x128 tile, BK=64, DOUBLE-BUFFERED LDS, ONE barrier per iter (32 iters).
// Swizzle: 128B rows = 8 chunks of 16B; phys chunk = logical ^ (row & 7).
// ---------------------------------------------------------------------------
__global__ __launch_bounds__(256) void out_gemm_kernel(
    const u16* __restrict__ Wmat, const u16* __restrict__ hT, float* __restrict__ out)
{
    __shared__ u16 As[2][128 * 64];
    __shared__ u16 Bs[2][128 * 64];
    int b = blockIdx.z;
    int q0 = blockIdx.x * 128, e0 = blockIdx.y * 128;
    int t = threadIdx.x, lane = t & 63, w = t >> 6;
    int l15 = lane & 15, quad = lane >> 4;
    const u16* Wb  = Wmat + (size_t)b * SEQ * SEQ;
    const u16* hTb = hT + (size_t)b * EMBED * SEQ;
    int wq = (w & 1) * 64, we = (w >> 1) * 64;

    f32x4 acc[4][4];
#pragma unroll
    for (int qi = 0; qi < 4; qi++)
#pragma unroll
        for (int ei = 0; ei < 4; ei++) acc[qi][ei] = (f32x4){0.f, 0.f, 0.f, 0.f};

    // staging mapping: per wave-call covers 8 rows x 8 chunks (lane = rl*8+pc)
    int st_rl = lane >> 3;            // row within 8-row group
    int st_pc = lane & 7;             // physical chunk at dest (= lane pattern)

    // stage rows [w*32, w*32+32) of As and Bs for k-chunk k0 into buffer `bi`
#define STAGE(bi, k0)                                                          \
    {                                                                          \
        _Pragma("unroll")                                                      \
        for (int ld = 0; ld < 4; ld++) {                                       \
            int rowb = w * 32 + ld * 8;                                        \
            int row  = rowb + st_rl;                                           \
            int cg   = st_pc ^ (row & 7); /* logical source chunk */           \
            gload_lds16(Wb  + (size_t)(q0 + row) * SEQ + (k0) + cg * 8,        \
                        &As[bi][rowb * 64] + lane * 8);                        \
            gload_lds16(hTb + (size_t)(e0 + row) * SEQ + (k0) + cg * 8,        \
                        &Bs[bi][rowb * 64] + lane * 8);                        \
        }                                                                      \
    }

    STAGE(0, 0)

    for (int it = 0; it < 32; ++it) {
        int buf = it & 1;
        __syncthreads();   // drains gloads for `buf`; guards reuse of buf^1
        if (it + 1 < 32) STAGE(buf ^ 1, (it + 1) * 64)

        short8 af[2][4], bfr[2][4];
#pragma unroll
        for (int kf = 0; kf < 2; kf++)
#pragma unroll
            for (int i = 0; i < 4; i++) {
                int ra = wq + i * 16 + l15;
                int rb = we + i * 16 + l15;
                int pca = (kf * 4 + quad) ^ (ra & 7);
                int pcb = (kf * 4 + quad) ^ (rb & 7);
                af[kf][i]  = *(const short8*)(&As[buf][ra * 64] + pca * 8);
                bfr[kf][i] = *(const short8*)(&Bs[buf][rb * 64] + pcb * 8);
            }
#pragma unroll
        for (int qi = 0; qi < 4; qi++)
#pragma unroll
            for (int ei = 0; ei < 4; ei++) {
                acc[qi][ei] = __builtin_amdgcn_mfma_f32_16x16x32_bf16(
                    af[0][qi], bfr[0][ei], acc[qi][ei], 0, 0, 0);
                acc[qi][ei] = __builtin_amdgcn_mfma_f32_16x16x32_bf16(
                    af[1][qi], bfr[1][ei], acc[qi][ei], 0, 0, 0);
            }
    }
#undef STAGE

    float* outb = out + (size_t)b * SEQ * EMBED;
#pragma unroll
    for (int qi = 0; qi < 4; qi++)
#pragma unroll
        for (int ei = 0; ei < 4; ei++)
#pragma unroll
            for (int r = 0; r < 4; r++)
                outb[(size_t)(q0 + wq + qi * 16 + quad * 4 + r) * EMBED
                     + e0 + we + ei * 16 + l15] = acc[qi][ei][r];
}

// ---------------------------------------------------------------------------
extern "C" void kernel_launch(void* const* d_in, const int* in_sizes, int n_in,
                              void* d_out, int out_size, void* d_ws, size_t ws_size,
                              hipStream_t stream) {
    (void)in_sizes; (void)n_in; (void)out_size; (void)ws_size;
    const float* h  = (const float*)d_in[0];
    const float* Wq = (const float*)d_in[1];
    const float* bq = (const float*)d_in[2];
    const float* Wk = (const float*)d_in[3];
    const float* bk = (const float*)d_in[4];
    // d_in[5], d_in[6] (Wv, bv) are dead in the reference.
    float* out = (float*)d_out;

    char* ws = (char*)d_ws;
    u16*   Qbf  = (u16*)(ws);                                  // 1 MB
    u16*   Kbf  = (u16*)(ws + (1ull << 20));                   // 1 MB
    u16*   hT   = (u16*)(ws + (2ull << 20));                   // 16 MB
    float* mArr = (float*)(ws + (18ull << 20));                // 32 KB
    float* lArr = (float*)(ws + (18ull << 20) + (64ull << 10));// 32 KB
    u16*   WqT  = (u16*)(ws + (18ull << 20) + (128ull << 10)); // 128 KB
    u16*   WkT  = (u16*)(ws + (18ull << 20) + (256ull << 10)); // 128 KB
    u16*   Wmat = (u16*)(ws + (19ull << 20));                  // 32 MB (total ~51 MB)

    hipLaunchKernelGGL(wt_kernel, dim3(16, 2), dim3(256), 0, stream, Wq, Wk, WqT, WkT);
    hipLaunchKernelGGL(proj_kernel, dim3(512), dim3(256), 0, stream,
                       h, WqT, WkT, bq, bk, Qbf, Kbf, hT);
    hipLaunchKernelGGL(stats_kernel, dim3(128, 4), dim3(256), 0, stream,
                       Qbf, Kbf, mArr, lArr);
    hipLaunchKernelGGL(weights_kernel, dim3(32, 32, 4), dim3(256), 0, stream,
                       Qbf, Kbf, mArr, lArr, Wmat);
    hipLaunchKernelGGL(out_gemm_kernel, dim3(16, 8, 4), dim3(256), 0, stream,
                       Wmat, hT, out);
}